// Round 5
// baseline (956.964 us; speedup 1.0000x reference)
//
#include <hip/hip_runtime.h>

// GRU4REC final-state kernel, v2: fp16-dot2 persistent-register weights,
// 2 blocks/CU to break barrier lockstep.
// B=1024, T=256, D=64, H=128.  Inputs fp32, h-state fp32, dot inputs fp16
// (v_dot2_f32_f16, fp32 accumulate), output fp32.
//
// 512 blocks x 1024 threads, G=2 rows/block, 2 blocks/CU (needs <=64 VGPR:
// weights = 36 packed-fp16 VGPRs/thread = one full copy per block).
// Phase lockstep of block A overlaps with block B -> LDS and VALU pipes
// both stay busy.

#define T_  256
#define D_  64
#define H_  128
#define DH_ 192
#define G_  2

typedef _Float16 half2v __attribute__((ext_vector_type(2)));

__device__ __forceinline__ float fdot2(half2v a, half2v b, float c) {
#if __has_builtin(__builtin_amdgcn_fdot2)
    return __builtin_amdgcn_fdot2(a, b, c, false);
#else
    return c + (float)a.x * (float)b.x + (float)a.y * (float)b.y;
#endif
}

__global__ __launch_bounds__(1024, 8) void gru_dot2(
    const int* __restrict__ item_his,          // [1024][256]
    const int* __restrict__ seq_lens,          // [1024]
    const float* __restrict__ emb,             // [1e6][64]
    const float* __restrict__ Wg,              // [192][256]
    const float* __restrict__ bg,              // [256]
    const float* __restrict__ Wc,              // [192][128]
    const float* __restrict__ bc,              // [128]
    float* __restrict__ out)                   // [1024][128] fp32
{
    __shared__ _Float16 XHh[G_][DH_];    // fp16 [x_t | h]      (dot input)
    __shared__ _Float16 XCh[G_][DH_];    // fp16 [x_t | r*h]    (dot input)
    __shared__ float    XH32[G_][H_];    // fp32 h state
    __shared__ float    U[G_][H_];       // update gate
    __shared__ float    P[16][G_][256];  // gate partials (32 KB)
    __shared__ float    P2[16][G_][128]; // cand partials (16 KB)

    const int tid  = threadIdx.x;
    const int row0 = blockIdx.x * G_;

    // ---- dot-phase mapping ----
    const int jg  = tid & 63;        // lane: j-group
    const int kc  = tid >> 6;        // wave: k-chunk 0..15
    const int j0  = jg * 4;          // gate: 4 consecutive j
    const int j0c = jg * 2;          // cand: 2 consecutive j
    const int k0  = kc * 12;         // 12 k per chunk

    // ---- pack weights into fp16 pairs along K (one full copy per block) ----
    half2v wgp[6][4];                // gate: 6 k-pairs x 4 j   (24 VGPR)
    half2v wcp[6][2];                // cand: 6 k-pairs x 2 j   (12 VGPR)
    #pragma unroll
    for (int p = 0; p < 6; ++p) {
        const int k = k0 + 2 * p;
        #pragma unroll
        for (int c = 0; c < 4; ++c) {
            half2v w;
            w.x = (_Float16)Wg[(k + 0) * 256 + j0 + c];
            w.y = (_Float16)Wg[(k + 1) * 256 + j0 + c];
            wgp[p][c] = w;
        }
        #pragma unroll
        for (int c = 0; c < 2; ++c) {
            half2v w;
            w.x = (_Float16)Wc[(k + 0) * 128 + j0c + c];
            w.y = (_Float16)Wc[(k + 1) * 128 + j0c + c];
            wcp[p][c] = w;
        }
    }

    const float bgB = bg[tid & 255];
    const float bcB = bc[tid & 127];

    // ---- sequence lengths ----
    const int len0 = seq_lens[row0 + 0];
    const int len1 = seq_lens[row0 + 1];
    const int maxlen = max(len0, len1);
    const int lenD = ((tid >> 7) & 1) ? len1 : len0;

    // ---- init: h = 0 (fp32 + fp16), x_0 ----
    if (tid < 256) {
        const int r = tid >> 7, j = tid & 127;
        XH32[r][j]     = 0.f;
        XHh[r][64 + j] = (_Float16)0.f;
    }
    const bool isLoader = (tid >= 512 && tid < 640);
    const int  lr = (tid >> 6) & 1;  // loader row
    const int  ld = tid & 63;        // loader dim
    if (isLoader && maxlen > 0) {
        const int idx = item_his[(row0 + lr) * T_ + 0];
        const _Float16 x = (_Float16)emb[idx * D_ + ld];
        XHh[lr][ld] = x;
        XCh[lr][ld] = x;
    }
    __syncthreads();

    for (int t = 0; t < maxlen; ++t) {
        // ---- prefetch x_{t+1} (committed to LDS in phase D) ----
        float xn = 0.f;
        const int tn = t + 1;
        if (isLoader && tn < T_) {
            const int idx = item_his[(row0 + lr) * T_ + tn];
            xn = emb[idx * D_ + ld];
        }

        // ---- Phase A: gate partials via fdot2 ----
        #pragma unroll
        for (int r = 0; r < G_; ++r) {
            const uint2 u0 = *(const uint2*)&XHh[r][k0 + 0];
            const uint2 u1 = *(const uint2*)&XHh[r][k0 + 4];
            const uint2 u2 = *(const uint2*)&XHh[r][k0 + 8];
            const unsigned ub[6] = {u0.x, u0.y, u1.x, u1.y, u2.x, u2.y};
            float a0 = 0.f, a1 = 0.f, a2 = 0.f, a3 = 0.f;
            #pragma unroll
            for (int p = 0; p < 6; ++p) {
                const half2v xk = __builtin_bit_cast(half2v, ub[p]);
                a0 = fdot2(xk, wgp[p][0], a0);
                a1 = fdot2(xk, wgp[p][1], a1);
                a2 = fdot2(xk, wgp[p][2], a2);
                a3 = fdot2(xk, wgp[p][3], a3);
            }
            float4 o = {a0, a1, a2, a3};
            *(float4*)&P[kc][r][j0] = o;
        }
        __syncthreads();

        // ---- Phase B: reduce gates, sigmoid, build r*h (fp16) and u ----
        if (tid < 512) {
            const int rB = (tid >> 8) & 1;
            const int jB = tid & 255;
            float s = bgB;
            #pragma unroll
            for (int q = 0; q < 16; ++q) s += P[q][rB][jB];
            const float g = 1.f / (1.f + __expf(-s));
            if (jB < 128) {
                XCh[rB][64 + jB] = (_Float16)(g * XH32[rB][jB]);   // r * h
            } else {
                U[rB][jB - 128] = g;                                // u
            }
        }
        __syncthreads();

        // ---- Phase C: cand partials via fdot2 ----
        #pragma unroll
        for (int r = 0; r < G_; ++r) {
            const uint2 u0 = *(const uint2*)&XCh[r][k0 + 0];
            const uint2 u1 = *(const uint2*)&XCh[r][k0 + 4];
            const uint2 u2 = *(const uint2*)&XCh[r][k0 + 8];
            const unsigned ub[6] = {u0.x, u0.y, u1.x, u1.y, u2.x, u2.y};
            float c0 = 0.f, c1 = 0.f;
            #pragma unroll
            for (int p = 0; p < 6; ++p) {
                const half2v xk = __builtin_bit_cast(half2v, ub[p]);
                c0 = fdot2(xk, wcp[p][0], c0);
                c1 = fdot2(xk, wcp[p][1], c1);
            }
            float2 o2 = {c0, c1};
            *(float2*)&P2[kc][r][j0c] = o2;
        }
        __syncthreads();

        // ---- Phase D: reduce cand, tanh, h update (masked); commit x_{t+1} ----
        if (tid < 256) {
            const int rD = tid >> 7;
            const int jD = tid & 127;
            float s = bcB;
            #pragma unroll
            for (int q = 0; q < 16; ++q) s += P2[q][rD][jD];
            s = fminf(fmaxf(s, -15.f), 15.f);
            const float e = __expf(2.f * s);
            const float c = (e - 1.f) / (e + 1.f);        // tanh
            const float u = U[rD][jD];
            float h = XH32[rD][jD];
            if (t < lenD) h = u * h + (1.f - u) * c;
            XH32[rD][jD]    = h;
            XHh[rD][64 + jD] = (_Float16)h;
        } else if (isLoader && tn < T_) {
            const _Float16 x = (_Float16)xn;
            XHh[lr][ld] = x;
            XCh[lr][ld] = x;
        }
        __syncthreads();
    }

    // ---- write final h (fp32) ----
    if (tid < 256) {
        const int rD = tid >> 7;
        const int jD = tid & 127;
        out[(row0 + rD) * H_ + jD] = XH32[rD][jD];
    }
}

extern "C" void kernel_launch(void* const* d_in, const int* in_sizes, int n_in,
                              void* d_out, int out_size, void* d_ws, size_t ws_size,
                              hipStream_t stream) {
    const int*   item_his = (const int*)d_in[0];
    const int*   seq_lens = (const int*)d_in[1];
    const float* emb      = (const float*)d_in[2];
    const float* Wg       = (const float*)d_in[3];
    const float* bg       = (const float*)d_in[4];
    const float* Wc       = (const float*)d_in[5];
    const float* bc       = (const float*)d_in[6];
    float*       out      = (float*)d_out;

    gru_dot2<<<512, 1024, 0, stream>>>(item_his, seq_lens, emb, Wg, bg, Wc, bc, out);
}

// Round 6
// 922.171 us; speedup vs baseline: 1.0377x; 1.0377x over previous
//
#include <hip/hip_runtime.h>

// GRU4REC v3: skewed two-group pipeline, fp16-dot2 persistent-register weights.
// B=1024, T=256, D=64, H=128. Inputs fp32, h-state fp32 (LDS), dot inputs fp16,
// output fp32.
//
// 256 blocks x 1024 threads, 1 block/CU, 4 rows/block.
// Block splits into two 512-thread groups (2 rows each), skewed by ONE phase:
// every barrier interval runs one dot phase (VALU) in one group concurrently
// with one reduce phase (LDS) in the other -> pipes overlap despite barriers.
// Each group holds a full fp16-packed weight copy: 144 halves = 72 VGPRs/thr.
// launch_bounds(1024,4) -> 128-VGPR budget (R5 showed 64-cap => scratch spill).

#define T_  256
#define D_  64
#define H_  128
#define DH_ 192

typedef _Float16 half2v __attribute__((ext_vector_type(2)));

__device__ __forceinline__ float fdot2(half2v a, half2v b, float c) {
#if __has_builtin(__builtin_amdgcn_fdot2)
    return __builtin_amdgcn_fdot2(a, b, c, false);
#else
    return c + (float)a.x * (float)b.x + (float)a.y * (float)b.y;
#endif
}

__global__ __launch_bounds__(1024, 4) void gru_skew(
    const int* __restrict__ item_his,          // [1024][256]
    const int* __restrict__ seq_lens,          // [1024]
    const float* __restrict__ emb,             // [1e6][64]
    const float* __restrict__ Wg,              // [192][256]
    const float* __restrict__ bg,              // [256]
    const float* __restrict__ Wc,              // [192][128]
    const float* __restrict__ bc,              // [128]
    float* __restrict__ out)                   // [1024][128] fp32
{
    __shared__ __align__(16) _Float16 XHh[4][DH_];   // fp16 [x | h]
    __shared__ __align__(16) _Float16 XCh[4][DH_];   // fp16 [x | r*h]
    __shared__ float XH32[4][H_];                    // fp32 h
    __shared__ float U[4][H_];                       // update gate
    __shared__ float P [8][4][256];                  // gate partials (32 KB)
    __shared__ float P2[8][4][128];                  // cand partials (16 KB)

    const int tid  = threadIdx.x;
    const int grp  = tid >> 9;           // 0 | 1
    const int ltid = tid & 511;
    const int r0   = grp * 2;            // group's local row base (rows r0, r0+1)
    const int row0 = blockIdx.x * 4;     // global row base

    // ---- dot mapping within group: 64 j-lanes x 8 k-chunks ----
    const int jg  = ltid & 63;
    const int kc  = ltid >> 6;           // 0..7
    const int j0  = jg * 4;              // gate: 4 consecutive j
    const int j0c = jg * 2;              // cand: 2 consecutive j
    const int k0  = kc * 24;             // 24 k per chunk

    // ---- pack weights (full copy per group): 48 + 24 VGPRs of half2 ----
    half2v wgp[12][4];
    half2v wcp[12][2];
    #pragma unroll
    for (int p = 0; p < 12; ++p) {
        const int k = k0 + 2 * p;
        const float4 ga = *(const float4*)(Wg + (k + 0) * 256 + j0);
        const float4 gb = *(const float4*)(Wg + (k + 1) * 256 + j0);
        half2v w;
        w.x = (_Float16)ga.x; w.y = (_Float16)gb.x; wgp[p][0] = w;
        w.x = (_Float16)ga.y; w.y = (_Float16)gb.y; wgp[p][1] = w;
        w.x = (_Float16)ga.z; w.y = (_Float16)gb.z; wgp[p][2] = w;
        w.x = (_Float16)ga.w; w.y = (_Float16)gb.w; wgp[p][3] = w;
        const float2 ca = *(const float2*)(Wc + (k + 0) * 128 + j0c);
        const float2 cb = *(const float2*)(Wc + (k + 1) * 128 + j0c);
        w.x = (_Float16)ca.x; w.y = (_Float16)cb.x; wcp[p][0] = w;
        w.x = (_Float16)ca.y; w.y = (_Float16)cb.y; wcp[p][1] = w;
    }

    const float bgB = bg[ltid & 255];    // phase B bias (j = ltid & 255)
    const float bcB = bc[ltid & 127];    // phase D bias (j = ltid & 127)

    // ---- sequence lengths ----
    const int l0 = seq_lens[row0 + 0];
    const int l1 = seq_lens[row0 + 1];
    const int l2 = seq_lens[row0 + 2];
    const int l3 = seq_lens[row0 + 3];
    const int maxlen = max(max(l0, l1), max(l2, l3));
    // phase-D row for ltid<256 threads: rD = r0 + (ltid>>7)
    const int lenD = seq_lens[row0 + r0 + ((ltid >> 7) & 1)];

    // ---- loaders (within group): 128 threads cover 2 rows x 64 dims ----
    const bool isLoader = (ltid >= 256 && ltid < 384);
    const int  lr = r0 + ((ltid >> 6) & 1);  // local row 0..3
    const int  ld = ltid & 63;

    // ---- init: h = 0; x_0 ----
    if (tid < 512) {
        const int r = tid >> 7, j = tid & 127;
        XH32[r][j]     = 0.f;
        XHh[r][64 + j] = (_Float16)0.f;
    }
    if (tid >= 512 && tid < 768 && maxlen > 0) {
        const int r  = (tid >> 6) & 3;
        const int dd = tid & 63;
        const int idx = item_his[(row0 + r) * T_ + 0];
        const _Float16 x = (_Float16)emb[idx * D_ + dd];
        XHh[r][dd] = x;
        XCh[r][dd] = x;
    }
    __syncthreads();

    const int nInt = (maxlen > 0) ? (4 * maxlen + 1) : 0;
    float xn = 0.f;   // prefetch register (loader threads), set in A, used in D

    for (int ii = 0; ii < nInt; ++ii) {
        int ph, tt;
        if (grp == 0) { tt = ii >> 2; ph = ii & 3; }
        else {
            const int jj = ii - 1;
            tt = jj >> 2;
            ph = (jj >= 0) ? (jj & 3) : -1;
        }
        if (tt >= maxlen) ph = -1;

        if (ph == 0) {
            // ---- issue x_{t+1} prefetch ----
            if (isLoader && tt + 1 < T_) {
                const int idx = item_his[(row0 + lr) * T_ + tt + 1];
                xn = emb[idx * D_ + ld];
            }
            // ---- Phase A: gate dots for rows r0, r0+1 ----
            #pragma unroll
            for (int rr = 0; rr < 2; ++rr) {
                const int r = r0 + rr;
                const uint4 a = *(const uint4*)&XHh[r][k0 + 0];
                const uint4 b = *(const uint4*)&XHh[r][k0 + 8];
                const uint4 c = *(const uint4*)&XHh[r][k0 + 16];
                const unsigned uw[12] = {a.x, a.y, a.z, a.w,
                                         b.x, b.y, b.z, b.w,
                                         c.x, c.y, c.z, c.w};
                float s0 = 0.f, s1 = 0.f, s2 = 0.f, s3 = 0.f;
                #pragma unroll
                for (int p = 0; p < 12; ++p) {
                    const half2v xk = __builtin_bit_cast(half2v, uw[p]);
                    s0 = fdot2(xk, wgp[p][0], s0);
                    s1 = fdot2(xk, wgp[p][1], s1);
                    s2 = fdot2(xk, wgp[p][2], s2);
                    s3 = fdot2(xk, wgp[p][3], s3);
                }
                float4 o = {s0, s1, s2, s3};
                *(float4*)&P[kc][r][j0] = o;
            }
        } else if (ph == 1) {
            // ---- Phase B: reduce gates, sigmoid, r*h and u ----
            const int rB = r0 + ((ltid >> 8) & 1);
            const int jB = ltid & 255;
            float s = bgB;
            #pragma unroll
            for (int q = 0; q < 8; ++q) s += P[q][rB][jB];
            const float g = 1.f / (1.f + __expf(-s));
            if (jB < 128) {
                XCh[rB][64 + jB] = (_Float16)(g * XH32[rB][jB]);   // r * h
            } else {
                U[rB][jB - 128] = g;                                // u
            }
        } else if (ph == 2) {
            // ---- Phase C: cand dots ----
            #pragma unroll
            for (int rr = 0; rr < 2; ++rr) {
                const int r = r0 + rr;
                const uint4 a = *(const uint4*)&XCh[r][k0 + 0];
                const uint4 b = *(const uint4*)&XCh[r][k0 + 8];
                const uint4 c = *(const uint4*)&XCh[r][k0 + 16];
                const unsigned uw[12] = {a.x, a.y, a.z, a.w,
                                         b.x, b.y, b.z, b.w,
                                         c.x, c.y, c.z, c.w};
                float s0 = 0.f, s1 = 0.f;
                #pragma unroll
                for (int p = 0; p < 12; ++p) {
                    const half2v xk = __builtin_bit_cast(half2v, uw[p]);
                    s0 = fdot2(xk, wcp[p][0], s0);
                    s1 = fdot2(xk, wcp[p][1], s1);
                }
                float2 o2 = {s0, s1};
                *(float2*)&P2[kc][r][j0c] = o2;
            }
        } else if (ph == 3) {
            // ---- Phase D: reduce cand, tanh, h update; commit prefetch ----
            if (ltid < 256) {
                const int rD = r0 + (ltid >> 7);
                const int jD = ltid & 127;
                float s = bcB;
                #pragma unroll
                for (int q = 0; q < 8; ++q) s += P2[q][rD][jD];
                s = fminf(fmaxf(s, -15.f), 15.f);
                const float e = __expf(2.f * s);
                const float c = (e - 1.f) / (e + 1.f);        // tanh
                const float u = U[rD][jD];
                float h = XH32[rD][jD];
                if (tt < lenD) h = u * h + (1.f - u) * c;
                XH32[rD][jD]     = h;
                XHh[rD][64 + jD] = (_Float16)h;
            } else if (isLoader && tt + 1 < T_) {
                const _Float16 x = (_Float16)xn;
                XHh[lr][ld] = x;
                XCh[lr][ld] = x;
            }
        }
        __syncthreads();
    }

    // ---- write final h (fp32) ----
    if (tid < 512) {
        const int r = tid >> 7, j = tid & 127;
        out[(row0 + r) * H_ + j] = XH32[r][j];
    }
}

extern "C" void kernel_launch(void* const* d_in, const int* in_sizes, int n_in,
                              void* d_out, int out_size, void* d_ws, size_t ws_size,
                              hipStream_t stream) {
    const int*   item_his = (const int*)d_in[0];
    const int*   seq_lens = (const int*)d_in[1];
    const float* emb      = (const float*)d_in[2];
    const float* Wg       = (const float*)d_in[3];
    const float* bg       = (const float*)d_in[4];
    const float* Wc       = (const float*)d_in[5];
    const float* bc       = (const float*)d_in[6];
    float*       out      = (float*)d_out;

    gru_skew<<<256, 1024, 0, stream>>>(item_his, seq_lens, emb, Wg, bg, Wc, bc, out);
}

// Round 7
// 644.894 us; speedup vs baseline: 1.4839x; 1.4300x over previous
//
#include <hip/hip_runtime.h>

// GRU4REC v4: MFMA-based. B=1024, T=256, D=64, H=128.
// 256 blocks x 512 threads (8 waves), 1 block/CU, 4 rows/block (M-pad to 16).
// Gate: [16x192]@[192x256] = 96 mfma_f32_16x16x32_f16 per step;
// Cand: [16x192]@[192x128] = 48.  K accumulates inside MFMA -> no LDS
// partials; 2 barriers/step.  Wave w owns columns [16w,16w+16): r,u,c and
// h-state all in the same lanes (C-layout col=lane&15,row=reg) -> h,u in
// registers.  LDS holds only fp16 A-operands [x|h], [x|r*h], 416 B stride.
// Weights persist as B-fragments: 18 half8 = 72 VGPRs/thread (256-reg budget
// at 8 waves/CU -> no spill; R5/R6 showed spill only under 64-reg caps).

#define T_   256
#define D_   64
#define H_   128
#define SROW 208   // halves per A-row (416 B): pad for bank spread, 16B-aligned

typedef _Float16 half8_t  __attribute__((ext_vector_type(8)));
typedef float    floatx4  __attribute__((ext_vector_type(4)));

__global__ __launch_bounds__(512, 2) void gru_mfma(
    const int* __restrict__ item_his,          // [1024][256]
    const int* __restrict__ seq_lens,          // [1024]
    const float* __restrict__ emb,             // [1e6][64]
    const float* __restrict__ Wg,              // [192][256]
    const float* __restrict__ bg,              // [256]
    const float* __restrict__ Wc,              // [192][128]
    const float* __restrict__ bc,              // [128]
    float* __restrict__ out)                   // [1024][128] fp32
{
    __shared__ __align__(16) _Float16 XA[16][SROW];  // [x | h]   (gate A)
    __shared__ __align__(16) _Float16 XC[16][SROW];  // [x | r*h] (cand A)

    const int tid  = threadIdx.x;
    const int w    = tid >> 6;        // wave 0..7
    const int lane = tid & 63;
    const int row0 = blockIdx.x * 4;

    // ---- persistent B-fragments ----
    // B-frag (K32xN16): lane holds B[k = kt*32 + (lane>>4)*8 + i][n = lane&15]
    const int bq = lane >> 4;         // k-quad
    const int bn = lane & 15;         // n within tile
    half8_t BG0[6], BG1[6], BC6[6];   // gate-r (nt=w), gate-u (nt=w+8), cand (nt=w)
    #pragma unroll
    for (int kt = 0; kt < 6; ++kt) {
        half8_t f0, f1, fc;
        #pragma unroll
        for (int i = 0; i < 8; ++i) {
            const int k = kt * 32 + bq * 8 + i;
            f0[i] = (_Float16)Wg[k * 256 + (w * 16 + bn)];
            f1[i] = (_Float16)Wg[k * 256 + (128 + w * 16 + bn)];
            fc[i] = (_Float16)Wc[k * 128 + (w * 16 + bn)];
        }
        BG0[kt] = f0; BG1[kt] = f1; BC6[kt] = fc;
    }

    // ---- biases for this wave's columns (col = lane&15) ----
    const float bgR = bg[w * 16 + bn];
    const float bgU = bg[128 + w * 16 + bn];
    const float bcC = bc[w * 16 + bn];

    // ---- sequence lengths ----
    int len[4];
    #pragma unroll
    for (int r = 0; r < 4; ++r) len[r] = seq_lens[row0 + r];
    const int maxlen = max(max(len[0], len[1]), max(len[2], len[3]));

    // ---- zero A-buffers (rows 4..15 stay zero forever) ----
    {
        unsigned* pa = (unsigned*)&XA[0][0];
        unsigned* pc = (unsigned*)&XC[0][0];
        for (int i = tid; i < 16 * SROW / 2; i += 512) { pa[i] = 0u; pc[i] = 0u; }
    }
    __syncthreads();

    // ---- x-gather mapping: 8 waves x lanes 0..31 cover 4 rows x 64 dims ----
    const int  row_l = w >> 1;
    const int  d_l   = (w & 1) * 32 + (lane & 31);
    const bool ldr   = (lane < 32);

    // ---- init: x_0 into XA/XC; h = 0 (register-resident) ----
    float xprev = 0.f;
    if (ldr) {
        const int idx = item_his[(row0 + row_l) * T_ + 0];
        xprev = emb[(size_t)idx * D_ + d_l];
        const _Float16 xh = (_Float16)xprev;
        XA[row_l][d_l] = xh;
        XC[row_l][d_l] = xh;
    }
    float h[4] = {0.f, 0.f, 0.f, 0.f};
    float u[4] = {0.f, 0.f, 0.f, 0.f};
    __syncthreads();

    for (int t = 0; t < maxlen; ++t) {
        // ================= Phase 1: gate =================
        // commit XC x-part <- x_t (read by cand in phase 2)
        if (ldr) XC[row_l][d_l] = (_Float16)xprev;
        // issue prefetch of x_{t+1}  (t+1 <= 255 always since len <= 255)
        float xnew = 0.f;
        if (ldr) {
            const int idx = item_his[(row0 + row_l) * T_ + (t + 1)];
            xnew = emb[(size_t)idx * D_ + d_l];
        }

        floatx4 aR = {0.f, 0.f, 0.f, 0.f};
        floatx4 aU = {0.f, 0.f, 0.f, 0.f};
        #pragma unroll
        for (int kt = 0; kt < 6; ++kt) {
            const half8_t af = *(const half8_t*)&XA[lane & 15][kt * 32 + (lane >> 4) * 8];
            aR = __builtin_amdgcn_mfma_f32_16x16x32_f16(af, BG0[kt], aR, 0, 0, 0);
            aU = __builtin_amdgcn_mfma_f32_16x16x32_f16(af, BG1[kt], aU, 0, 0, 0);
        }
        // valid C rows 0..3 live in lanes 0..15 (row = reg, col = lane)
        if (lane < 16) {
            #pragma unroll
            for (int r = 0; r < 4; ++r) {
                const float rg = 1.f / (1.f + __expf(-(aR[r] + bgR)));
                u[r]           = 1.f / (1.f + __expf(-(aU[r] + bgU)));
                XC[r][64 + w * 16 + lane] = (_Float16)(rg * h[r]);   // r * h
            }
        }
        __syncthreads();

        // ================= Phase 2: cand + h update =================
        // commit XA x-part <- x_{t+1} (read by gate at t+1)
        if (ldr) XA[row_l][d_l] = (_Float16)xnew;

        floatx4 aC = {0.f, 0.f, 0.f, 0.f};
        #pragma unroll
        for (int kt = 0; kt < 6; ++kt) {
            const half8_t af = *(const half8_t*)&XC[lane & 15][kt * 32 + (lane >> 4) * 8];
            aC = __builtin_amdgcn_mfma_f32_16x16x32_f16(af, BC6[kt], aC, 0, 0, 0);
        }
        if (lane < 16) {
            #pragma unroll
            for (int r = 0; r < 4; ++r) {
                float s = aC[r] + bcC;
                s = fminf(fmaxf(s, -15.f), 15.f);
                const float e = __expf(2.f * s);
                const float c = (e - 1.f) / (e + 1.f);          // tanh
                const float hn = u[r] * h[r] + (1.f - u[r]) * c;
                if (t < len[r]) h[r] = hn;                       // copy-through mask
                XA[r][64 + w * 16 + lane] = (_Float16)h[r];
            }
        }
        xprev = xnew;
        __syncthreads();
    }

    // ---- write final h (fp32): wave w covers cols [16w, 16w+16) ----
    if (lane < 16) {
        #pragma unroll
        for (int r = 0; r < 4; ++r)
            out[(row0 + r) * H_ + w * 16 + lane] = h[r];
    }
}

extern "C" void kernel_launch(void* const* d_in, const int* in_sizes, int n_in,
                              void* d_out, int out_size, void* d_ws, size_t ws_size,
                              hipStream_t stream) {
    const int*   item_his = (const int*)d_in[0];
    const int*   seq_lens = (const int*)d_in[1];
    const float* emb      = (const float*)d_in[2];
    const float* Wg       = (const float*)d_in[3];
    const float* bg       = (const float*)d_in[4];
    const float* Wc       = (const float*)d_in[5];
    const float* bc       = (const float*)d_in[6];
    float*       out      = (float*)d_out;

    gru_mfma<<<256, 512, 0, stream>>>(item_his, seq_lens, emb, Wg, bg, Wc, bc, out);
}